// Round 3
// baseline (190.611 us; speedup 1.0000x reference)
//
#include <hip/hip_runtime.h>
#include <math.h>

#define BB 4
#define NN 6
#define DD 41
#define CC 64
#define FHh 16
#define FWw 44
#define NXg 200
#define NYg 200
#define NZg 1
#define NPIX (BB*NN*FHh*FWw)   // 16896

__device__ __forceinline__ void inv3x3d(const double m[9], double o[9]) {
    double a=m[0],b=m[1],c=m[2],d=m[3],e=m[4],f=m[5],g=m[6],h=m[7],i=m[8];
    double A = e*i - f*h;
    double Bv = -(d*i - f*g);
    double Cv = d*h - e*g;
    double det = a*A + b*Bv + c*Cv;
    double r = 1.0/det;
    o[0]=A*r;  o[1]=-(b*i-c*h)*r; o[2]=(b*f-c*e)*r;
    o[3]=Bv*r; o[4]=(a*i-c*g)*r;  o[5]=-(a*f-c*d)*r;
    o[6]=Cv*r; o[7]=-(a*h-b*g)*r; o[8]=(a*e-b*d)*r;
}

// MODE 0: accumulate into ws laid out [B*NZ*NX*NY][CC]  (channel-innermost)
// MODE 1: accumulate directly into out laid out [B*NZ][CC][NX*NY]
template<int MODE>
__global__ __launch_bounds__(256)
void lss_scatter(const float* __restrict__ xf,
                 const float* __restrict__ rots,
                 const float* __restrict__ trans,
                 const float* __restrict__ intr,
                 const float* __restrict__ prots,
                 const float* __restrict__ ptrans,
                 float* __restrict__ acc)
{
    const int wid  = blockIdx.x * 4 + (threadIdx.x >> 6);
    const int lane = threadIdx.x & 63;
    if (wid >= NPIX) return;
    int w  = wid % FWw;
    int t1 = wid / FWw;
    int h  = t1 % FHh; t1 /= FHh;
    int n  = t1 % NN;
    int b  = t1 / NN;
    const int cam = b*NN + n;

    // ---- per-camera transform (double precision, redundant per lane) ----
    double K9[9], P9[9], R9[9];
    #pragma unroll
    for (int i = 0; i < 9; ++i) {
        K9[i] = (double)intr [cam*9 + i];
        P9[i] = (double)prots[cam*9 + i];
        R9[i] = (double)rots [cam*9 + i];
    }
    double Kinv[9], Pinv[9];
    inv3x3d(K9, Kinv);
    inv3x3d(P9, Pinv);
    double M[9];
    #pragma unroll
    for (int i = 0; i < 3; ++i)
        #pragma unroll
        for (int j = 0; j < 3; ++j)
            M[i*3+j] = R9[i*3+0]*Kinv[0*3+j] + R9[i*3+1]*Kinv[1*3+j] + R9[i*3+2]*Kinv[2*3+j];
    const double tx  = (double)trans [cam*3+0], ty  = (double)trans [cam*3+1], tz  = (double)trans [cam*3+2];
    const double ptx = (double)ptrans[cam*3+0], pty = (double)ptrans[cam*3+1], ptz = (double)ptrans[cam*3+2];

    // ---- depth softmax over 41 logits (lanes 0..40) ----
    const size_t pixoff = (size_t)cam * (DD+CC) * FHh * FWw + (size_t)h * FWw + w;
    float logit = (lane < DD) ? xf[pixoff + (size_t)lane * (FHh*FWw)] : -INFINITY;
    float mx = logit;
    #pragma unroll
    for (int off = 32; off; off >>= 1) mx = fmaxf(mx, __shfl_xor(mx, off));
    float ex = (lane < DD) ? expf(logit - mx) : 0.0f;
    float sm = ex;
    #pragma unroll
    for (int off = 32; off; off >>= 1) sm += __shfl_xor(sm, off);
    const float wgt = ex / sm;

    // ---- geometry for lane's depth bin -> accumulation base address ----
    int baddr = -1;
    if (lane < DD) {
        double dz = 4.0 + (double)lane;
        double xs = (double)w * (703.0/43.0);
        double ys = (double)h * 17.0;
        double px = xs - ptx, py = ys - pty, pz = dz - ptz;
        double qx = Pinv[0]*px + Pinv[1]*py + Pinv[2]*pz;
        double qy = Pinv[3]*px + Pinv[4]*py + Pinv[5]*pz;
        double qz = Pinv[6]*px + Pinv[7]*py + Pinv[8]*pz;
        qx *= qz; qy *= qz;
        double gx = M[0]*qx + M[1]*qy + M[2]*qz + tx;
        double gy = M[3]*qx + M[4]*qy + M[5]*qz + ty;
        double gz = M[6]*qx + M[7]*qy + M[8]*qz + tz;
        double fx = floor((gx + 50.0) / 0.5);
        double fy = floor((gy + 50.0) / 0.5);
        double fz = floor((gz + 10.0) / 20.0);
        if (fx >= 0.0 && fx < (double)NXg &&
            fy >= 0.0 && fy < (double)NYg &&
            fz >= 0.0 && fz < (double)NZg) {
            int ix = (int)fx, iy = (int)fy, iz = (int)fz;
            if (MODE == 0) {
                int seg = ((b*NZg + iz)*NXg + ix)*NYg + iy;
                baddr = seg * CC;
            } else {
                int bz = b*NZg + iz;
                baddr = bz * (CC*NXg*NYg) + ix*NYg + iy;
            }
        }
    }

    // ---- per-channel feature, scatter over depth bins ----
    const float f = xf[pixoff + (size_t)(DD + lane) * (FHh*FWw)];
    const int cmul = (MODE == 0) ? 1 : (NXg*NYg);

    for (int d = 0; d < DD; ++d) {
        int   a  = __shfl(baddr, d);
        float wd = __shfl(wgt,   d);
        if (a >= 0) atomicAdd(&acc[(size_t)a + (size_t)lane * cmul], wd * f);
    }
}

// ws [B*NZ][40000 xy][64 c]  ->  out [B*NZ][64 c][40000 xy]
__global__ __launch_bounds__(256)
void lss_transpose(const float* __restrict__ ws, float* __restrict__ out)
{
    __shared__ float tile[64][65];
    const int blk  = blockIdx.x;            // B*NZ*625 blocks
    const int bz   = blk / 625;
    const int xy0  = (blk % 625) * 64;
    const int lane = threadIdx.x & 63;
    const int grp  = threadIdx.x >> 6;      // 0..3

    const float* src = ws + ((size_t)bz * 40000 + xy0) * CC;
    #pragma unroll
    for (int i = 0; i < 16; ++i) {
        int r = grp * 16 + i;
        tile[r][lane] = src[(size_t)r * CC + lane];
    }
    __syncthreads();
    float* dst = out + (size_t)bz * CC * 40000 + xy0;
    #pragma unroll
    for (int i = 0; i < 16; ++i) {
        int cRow = grp * 16 + i;
        dst[(size_t)cRow * 40000 + lane] = tile[lane][cRow];
    }
}

extern "C" void kernel_launch(void* const* d_in, const int* in_sizes, int n_in,
                              void* d_out, int out_size, void* d_ws, size_t ws_size,
                              hipStream_t stream) {
    const float* xf     = (const float*)d_in[0];
    const float* rots   = (const float*)d_in[1];
    const float* trans  = (const float*)d_in[2];
    const float* intr   = (const float*)d_in[3];
    const float* prots  = (const float*)d_in[4];
    const float* ptrans = (const float*)d_in[5];
    float* out = (float*)d_out;

    const size_t need = (size_t)BB * NZg * NXg * NYg * CC * sizeof(float); // 40.96 MB
    dim3 blk(256);
    dim3 grid((NPIX + 3) / 4);

    if (ws_size >= need) {
        float* ws = (float*)d_ws;
        hipMemsetAsync(ws, 0, need, stream);
        lss_scatter<0><<<grid, blk, 0, stream>>>(xf, rots, trans, intr, prots, ptrans, ws);
        lss_transpose<<<dim3(BB*NZg*625), dim3(256), 0, stream>>>(ws, out);
    } else {
        hipMemsetAsync(out, 0, need, stream);
        lss_scatter<1><<<grid, blk, 0, stream>>>(xf, rots, trans, intr, prots, ptrans, out);
    }
}

// Round 4
// 55.438 us; speedup vs baseline: 3.4383x; 3.4383x over previous
//
#include <hip/hip_runtime.h>
#include <math.h>

#define BB 4
#define NN 6
#define DD 41
#define CC 64
#define FHh 16
#define FWw 44
#define NXg 200
#define NYg 200
#define NZg 1
#define NPIX (BB*NN*FHh*FWw)   // 16896
#define NSLOT 256
#define NOVF  (FHh*DD)         // 656 max points per column

__device__ __forceinline__ void inv3x3d(const double m[9], double o[9]) {
    double a=m[0],b=m[1],c=m[2],d=m[3],e=m[4],f=m[5],g=m[6],h=m[7],i=m[8];
    double A = e*i - f*h;
    double Bv = -(d*i - f*g);
    double Cv = d*h - e*g;
    double det = a*A + b*Bv + c*Cv;
    double r = 1.0/det;
    o[0]=A*r;  o[1]=-(b*i-c*h)*r; o[2]=(b*f-c*e)*r;
    o[3]=Bv*r; o[4]=(a*i-c*g)*r;  o[5]=-(a*f-c*d)*r;
    o[6]=Cv*r; o[7]=-(a*h-b*g)*r; o[8]=(a*e-b*d)*r;
}

// One block per (b,n,w) column. Dedup voxels in an LDS hash table, then one
// wave-wide atomic per unique voxel into ws[seg][64c] (channel-innermost).
__global__ __launch_bounds__(256)
void lss_scatter_dedup(const float* __restrict__ xf,
                       const float* __restrict__ rots,
                       const float* __restrict__ trans,
                       const float* __restrict__ intr,
                       const float* __restrict__ prots,
                       const float* __restrict__ ptrans,
                       float* __restrict__ ws)
{
    __shared__ int   s_keys[NSLOT];
    __shared__ float s_coef[NSLOT * FHh];
    __shared__ float s_feat[FHh * CC];
    __shared__ int2  s_ovf[NOVF];
    __shared__ float s_ovfw[NOVF];
    __shared__ int   s_ovfcnt;

    const int tid  = threadIdx.x;
    const int lane = tid & 63;
    const int wv   = tid >> 6;          // 0..3

    const int bid = blockIdx.x;         // 0..1055
    const int w   = bid % FWw;
    const int rem = bid / FWw;
    const int n   = rem % NN;
    const int b   = rem / NN;
    const int cam = b*NN + n;
    const size_t pixoff = (size_t)cam * (DD+CC) * FHh * FWw + w;

    // ---- init LDS + stage features [16h][64c] ----
    s_keys[tid] = -1;
    #pragma unroll
    for (int i = tid; i < NSLOT*FHh; i += 256) s_coef[i] = 0.0f;
    if (tid == 0) s_ovfcnt = 0;
    #pragma unroll
    for (int i = tid; i < FHh*CC; i += 256) {
        int c = i & 63, h = i >> 6;
        s_feat[i] = xf[pixoff + (size_t)(DD + c) * (FHh*FWw) + h * FWw];
    }

    // ---- per-camera transform (double precision, redundant per thread) ----
    double K9[9], P9[9], R9[9];
    #pragma unroll
    for (int i = 0; i < 9; ++i) {
        K9[i] = (double)intr [cam*9 + i];
        P9[i] = (double)prots[cam*9 + i];
        R9[i] = (double)rots [cam*9 + i];
    }
    double Kinv[9], Pinv[9];
    inv3x3d(K9, Kinv);
    inv3x3d(P9, Pinv);
    double M[9];
    #pragma unroll
    for (int i = 0; i < 3; ++i)
        #pragma unroll
        for (int j = 0; j < 3; ++j)
            M[i*3+j] = R9[i*3+0]*Kinv[0*3+j] + R9[i*3+1]*Kinv[1*3+j] + R9[i*3+2]*Kinv[2*3+j];
    const double tx  = (double)trans [cam*3+0], ty  = (double)trans [cam*3+1], tz  = (double)trans [cam*3+2];
    const double ptx = (double)ptrans[cam*3+0], pty = (double)ptrans[cam*3+1], ptz = (double)ptrans[cam*3+2];

    __syncthreads();

    // ---- softmax + geometry + hash insert; wave wv handles h = wv*4..wv*4+3
    for (int r = 0; r < 4; ++r) {
        const int h = (wv << 2) + r;
        float logit = (lane < DD)
            ? xf[pixoff + (size_t)lane * (FHh*FWw) + h * FWw] : -INFINITY;
        float mx = logit;
        #pragma unroll
        for (int off = 32; off; off >>= 1) mx = fmaxf(mx, __shfl_xor(mx, off));
        float ex = (lane < DD) ? expf(logit - mx) : 0.0f;
        float sm = ex;
        #pragma unroll
        for (int off = 32; off; off >>= 1) sm += __shfl_xor(sm, off);
        const float wgt = ex / sm;

        int seg = -1;
        if (lane < DD) {
            double dz = 4.0 + (double)lane;
            double xs = (double)w * (703.0/43.0);
            double ys = (double)h * 17.0;
            double px = xs - ptx, py = ys - pty, pz = dz - ptz;
            double qx = Pinv[0]*px + Pinv[1]*py + Pinv[2]*pz;
            double qy = Pinv[3]*px + Pinv[4]*py + Pinv[5]*pz;
            double qz = Pinv[6]*px + Pinv[7]*py + Pinv[8]*pz;
            qx *= qz; qy *= qz;
            double gx = M[0]*qx + M[1]*qy + M[2]*qz + tx;
            double gy = M[3]*qx + M[4]*qy + M[5]*qz + ty;
            double gz = M[6]*qx + M[7]*qy + M[8]*qz + tz;
            double fx = floor((gx + 50.0) / 0.5);
            double fy = floor((gy + 50.0) / 0.5);
            double fz = floor((gz + 10.0) / 20.0);
            if (fx >= 0.0 && fx < (double)NXg &&
                fy >= 0.0 && fy < (double)NYg &&
                fz >= 0.0 && fz < (double)NZg) {
                int ix = (int)fx, iy = (int)fy, iz = (int)fz;
                seg = ((b*NZg + iz)*NXg + ix)*NYg + iy;
            }
        }

        if (seg >= 0) {
            unsigned slot = (((unsigned)seg * 2654435761u) >> 20) & (NSLOT-1);
            bool done = false;
            for (int probe = 0; probe < NSLOT; ++probe) {
                int prev = atomicCAS(&s_keys[slot], -1, seg);
                if (prev == -1 || prev == seg) {
                    atomicAdd(&s_coef[slot*FHh + h], wgt);
                    done = true;
                    break;
                }
                slot = (slot + 1) & (NSLOT-1);
            }
            if (!done) {   // table full: spill (generic-correctness fallback)
                int k = atomicAdd(&s_ovfcnt, 1);
                s_ovf[k]  = make_int2(seg, h);
                s_ovfw[k] = wgt;
            }
        }
    }

    __syncthreads();

    // ---- emit: one wave-wide atomic per occupied slot ----
    for (int s = wv; s < NSLOT; s += 4) {
        int key = s_keys[s];
        if (key < 0) continue;
        float acc = 0.0f;
        #pragma unroll
        for (int h = 0; h < FHh; ++h)
            acc += s_coef[s*FHh + h] * s_feat[(h << 6) + lane];
        atomicAdd(&ws[(size_t)key * CC + lane], acc);
    }
    // ---- overflow entries (rare) ----
    const int novf = s_ovfcnt;
    for (int e = wv; e < novf; e += 4) {
        int seg = s_ovf[e].x, h = s_ovf[e].y;
        atomicAdd(&ws[(size_t)seg * CC + lane], s_ovfw[e] * s_feat[(h << 6) + lane]);
    }
}

// Fallback (ws too small): direct atomics into out [B*NZ][CC][NX*NY]
__global__ __launch_bounds__(256)
void lss_scatter_direct(const float* __restrict__ xf,
                        const float* __restrict__ rots,
                        const float* __restrict__ trans,
                        const float* __restrict__ intr,
                        const float* __restrict__ prots,
                        const float* __restrict__ ptrans,
                        float* __restrict__ acc)
{
    const int wid  = blockIdx.x * 4 + (threadIdx.x >> 6);
    const int lane = threadIdx.x & 63;
    if (wid >= NPIX) return;
    int w  = wid % FWw;
    int t1 = wid / FWw;
    int h  = t1 % FHh; t1 /= FHh;
    int n  = t1 % NN;
    int b  = t1 / NN;
    const int cam = b*NN + n;

    double K9[9], P9[9], R9[9];
    #pragma unroll
    for (int i = 0; i < 9; ++i) {
        K9[i] = (double)intr [cam*9 + i];
        P9[i] = (double)prots[cam*9 + i];
        R9[i] = (double)rots [cam*9 + i];
    }
    double Kinv[9], Pinv[9];
    inv3x3d(K9, Kinv);
    inv3x3d(P9, Pinv);
    double M[9];
    #pragma unroll
    for (int i = 0; i < 3; ++i)
        #pragma unroll
        for (int j = 0; j < 3; ++j)
            M[i*3+j] = R9[i*3+0]*Kinv[0*3+j] + R9[i*3+1]*Kinv[1*3+j] + R9[i*3+2]*Kinv[2*3+j];
    const double tx  = (double)trans [cam*3+0], ty  = (double)trans [cam*3+1], tz  = (double)trans [cam*3+2];
    const double ptx = (double)ptrans[cam*3+0], pty = (double)ptrans[cam*3+1], ptz = (double)ptrans[cam*3+2];

    const size_t pixoff = (size_t)cam * (DD+CC) * FHh * FWw + (size_t)h * FWw + w;
    float logit = (lane < DD) ? xf[pixoff + (size_t)lane * (FHh*FWw)] : -INFINITY;
    float mx = logit;
    #pragma unroll
    for (int off = 32; off; off >>= 1) mx = fmaxf(mx, __shfl_xor(mx, off));
    float ex = (lane < DD) ? expf(logit - mx) : 0.0f;
    float sm = ex;
    #pragma unroll
    for (int off = 32; off; off >>= 1) sm += __shfl_xor(sm, off);
    const float wgt = ex / sm;

    int baddr = -1;
    if (lane < DD) {
        double dz = 4.0 + (double)lane;
        double xs = (double)w * (703.0/43.0);
        double ys = (double)h * 17.0;
        double px = xs - ptx, py = ys - pty, pz = dz - ptz;
        double qx = Pinv[0]*px + Pinv[1]*py + Pinv[2]*pz;
        double qy = Pinv[3]*px + Pinv[4]*py + Pinv[5]*pz;
        double qz = Pinv[6]*px + Pinv[7]*py + Pinv[8]*pz;
        qx *= qz; qy *= qz;
        double gx = M[0]*qx + M[1]*qy + M[2]*qz + tx;
        double gy = M[3]*qx + M[4]*qy + M[5]*qz + ty;
        double gz = M[6]*qx + M[7]*qy + M[8]*qz + tz;
        double fx = floor((gx + 50.0) / 0.5);
        double fy = floor((gy + 50.0) / 0.5);
        double fz = floor((gz + 10.0) / 20.0);
        if (fx >= 0.0 && fx < (double)NXg &&
            fy >= 0.0 && fy < (double)NYg &&
            fz >= 0.0 && fz < (double)NZg) {
            int ix = (int)fx, iy = (int)fy, iz = (int)fz;
            int bz = b*NZg + iz;
            baddr = bz * (CC*NXg*NYg) + ix*NYg + iy;
        }
    }

    const float f = xf[pixoff + (size_t)(DD + lane) * (FHh*FWw)];
    for (int d = 0; d < DD; ++d) {
        int   a  = __shfl(baddr, d);
        float wd = __shfl(wgt,   d);
        if (a >= 0) atomicAdd(&acc[(size_t)a + (size_t)lane * (NXg*NYg)], wd * f);
    }
}

// ws [B*NZ][40000 xy][64 c]  ->  out [B*NZ][64 c][40000 xy]
__global__ __launch_bounds__(256)
void lss_transpose(const float* __restrict__ ws, float* __restrict__ out)
{
    __shared__ float tile[64][65];
    const int blk  = blockIdx.x;            // B*NZ*625 blocks
    const int bz   = blk / 625;
    const int xy0  = (blk % 625) * 64;
    const int lane = threadIdx.x & 63;
    const int grp  = threadIdx.x >> 6;      // 0..3

    const float* src = ws + ((size_t)bz * 40000 + xy0) * CC;
    #pragma unroll
    for (int i = 0; i < 16; ++i) {
        int r = grp * 16 + i;
        tile[r][lane] = src[(size_t)r * CC + lane];
    }
    __syncthreads();
    float* dst = out + (size_t)bz * CC * 40000 + xy0;
    #pragma unroll
    for (int i = 0; i < 16; ++i) {
        int cRow = grp * 16 + i;
        dst[(size_t)cRow * 40000 + lane] = tile[lane][cRow];
    }
}

extern "C" void kernel_launch(void* const* d_in, const int* in_sizes, int n_in,
                              void* d_out, int out_size, void* d_ws, size_t ws_size,
                              hipStream_t stream) {
    const float* xf     = (const float*)d_in[0];
    const float* rots   = (const float*)d_in[1];
    const float* trans  = (const float*)d_in[2];
    const float* intr   = (const float*)d_in[3];
    const float* prots  = (const float*)d_in[4];
    const float* ptrans = (const float*)d_in[5];
    float* out = (float*)d_out;

    const size_t need = (size_t)BB * NZg * NXg * NYg * CC * sizeof(float); // 40.96 MB

    if (ws_size >= need) {
        float* ws = (float*)d_ws;
        hipMemsetAsync(ws, 0, need, stream);
        lss_scatter_dedup<<<dim3(BB*NN*FWw), dim3(256), 0, stream>>>(
            xf, rots, trans, intr, prots, ptrans, ws);
        lss_transpose<<<dim3(BB*NZg*625), dim3(256), 0, stream>>>(ws, out);
    } else {
        hipMemsetAsync(out, 0, need, stream);
        lss_scatter_direct<<<dim3((NPIX + 3) / 4), dim3(256), 0, stream>>>(
            xf, rots, trans, intr, prots, ptrans, out);
    }
}